// Round 9
// baseline (127.822 us; speedup 1.0000x reference)
//
#include <hip/hip_runtime.h>
#include <hip/hip_bf16.h>

// B=8, C=64, O=64, H=W=128, stride=1, pad=1, 3x3.
constexpr int Bc = 8;
constexpr int Cc = 64;
constexpr int Oc = 64;
constexpr int Hc = 128;
constexpr int Wc = 128;
constexpr int HWc = Hc * Wc;

typedef __attribute__((ext_vector_type(8))) short short8;   // 8 x bf16
typedef __attribute__((ext_vector_type(4))) float floatx4;
typedef __attribute__((ext_vector_type(2))) float floatx2;
typedef __attribute__((ext_vector_type(4))) unsigned uintx4;

__device__ __forceinline__ float bperm(int idx4, float v) {
    return __int_as_float(__builtin_amdgcn_ds_bpermute(idx4, __float_as_int(v)));
}
// packed f32x2 -> bf16x2 (RNE), lo -> bits[15:0]
__device__ __forceinline__ unsigned cvt_pk_bf16(float lo, float hi) {
    unsigned r;
    asm("v_cvt_pk_bf16_f32 %0, %1, %2" : "=v"(r) : "v"(lo), "v"(hi));
    return r;
}

// v9: TWO-KERNEL SPLIT (v4-v8 post-mortem: five schedule variants of the
// fused block all pinned at 22-25us vs ~9us streaming floor -> the fused
// producer->LDS->GEMM coupling itself is the invariant; phases sum).
// K1 sel-producer: v7's tap machinery, sel+center held packed-bf16 in REGS,
//   one barrier (divp reduce), unconditional packed mask-select (no fixup
//   path, NO selT LDS), writes sel to d_ws in [b][p][c] bf16 (16 MB).
// K2 GEMM: NO LDS, NO barrier. [p][c] layout => B-fragment = contiguous 16B
//   global load (sel[p0+n][quad*8..+7]) - the fragment transpose disappears.
//   8 tiles/wave x (2 b128 + 2 MFMA + 4 stores); VGPR ~45, 16 waves/CU.
// Both kernels use b=blk&7 => same XCD touches the same image's sel: 2MB/XCD
// stays L2-resident between dispatches -> sel reads ~free at HBM.
__global__ __launch_bounds__(256, 4) void sel_kernel(
    const float* __restrict__ x, const float* __restrict__ peri,
    const float* __restrict__ thr, const float* __restrict__ scl,
    unsigned short* __restrict__ selws)
{
    __shared__ float s_divp[4][Wc];             // 2048 B (only LDS)

    const int tid = threadIdx.x;
    const int l   = tid & 63;                   // lane
    const int wv  = tid >> 6;                   // wave 0..3
    const int b   = blockIdx.x & 7;             // one image per XCD
    const int h   = blockIdx.x >> 3;            // row 0..127
    const int c0  = wv * 16;                    // wave's 16 channels

    const int upIdx = ((l - 1) & 63) << 2;      // bperm byte idx: lane l-1
    const int dnIdx = ((l + 1) & 63) << 2;      // lane l+1
    const float lzf = (l == 0)  ? 0.f : 1.f;    // w=0 left pad
    const float rzf = (l == 63) ? 0.f : 1.f;    // w=127 right pad
    const float mUf = (h > 0) ? 1.f : 0.f;
    const float mDf = (h < Hc - 1) ? 1.f : 0.f;
    const int   dU  = (h > 0) ? -Wc : 0;        // clamped row offsets
    const int   dD  = (h < Hc - 1) ? Wc : 0;

    const float p0 = peri[0], p1 = peri[1], p2 = peri[2], p3 = peri[3];
    const float p4 = peri[4], p5 = peri[5], p6 = peri[6], p7 = peri[7];
    const float thrv = thr[0], sclv = scl[0];

    const float* xw = x + (size_t)b * Cc * HWc + (size_t)h * Wc + 2 * l;

    float dlo = 0.f, dhi = 0.f;
    unsigned aggLoPk[8], aggHiPk[8], cenLoPk[8], cenHiPk[8];

// One channel: RM/R0/R1 = rows h-1,h,h+1 (vert pre-masked), K = slot in pair.
#define PROC1(RM, R0, R1, K) do {                                             \
    const float rmL = lzf * bperm(upIdx, RM.y);                               \
    const float r0L = lzf * bperm(upIdx, R0.y);                               \
    const float r1L = lzf * bperm(upIdx, R1.y);                               \
    const float rmR = rzf * bperm(dnIdx, RM.x);                               \
    const float r0R = rzf * bperm(dnIdx, R0.x);                               \
    const float r1R = rzf * bperm(dnIdx, R1.x);                               \
    { const float t = R0.x;  /* pixel lo (w=2l) */                            \
      float a = p0 * rmL; a = fmaf(p1, RM.x, a); a = fmaf(p2, RM.y, a);       \
      a = fmaf(p3, r0L, a); a = fmaf(p4, R0.y, a);                            \
      a = fmaf(p5, r1L, a); a = fmaf(p6, R1.x, a); a = fmaf(p7, R1.y, a);     \
      aLo[K] = a; float e;                                                    \
      e = rmL  - t; dlo = fmaf(e, e, dlo); e = RM.x - t; dlo = fmaf(e, e, dlo); \
      e = RM.y - t; dlo = fmaf(e, e, dlo); e = r0L  - t; dlo = fmaf(e, e, dlo); \
      e = R0.y - t; dlo = fmaf(e, e, dlo); e = r1L  - t; dlo = fmaf(e, e, dlo); \
      e = R1.x - t; dlo = fmaf(e, e, dlo); e = R1.y - t; dlo = fmaf(e, e, dlo); } \
    { const float t = R0.y;  /* pixel hi (w=2l+1) */                          \
      float a = p0 * RM.x; a = fmaf(p1, RM.y, a); a = fmaf(p2, rmR, a);       \
      a = fmaf(p3, R0.x, a); a = fmaf(p4, r0R, a);                            \
      a = fmaf(p5, R1.x, a); a = fmaf(p6, R1.y, a); a = fmaf(p7, r1R, a);     \
      aHi[K] = a; float e;                                                    \
      e = RM.x - t; dhi = fmaf(e, e, dhi); e = RM.y - t; dhi = fmaf(e, e, dhi); \
      e = rmR  - t; dhi = fmaf(e, e, dhi); e = R0.x - t; dhi = fmaf(e, e, dhi); \
      e = r0R  - t; dhi = fmaf(e, e, dhi); e = R1.x - t; dhi = fmaf(e, e, dhi); \
      e = R1.y - t; dhi = fmaf(e, e, dhi); e = r1R  - t; dhi = fmaf(e, e, dhi); } \
} while (0)

    #pragma unroll 2
    for (int j = 0; j < 8; ++j) {               // 8 channel pairs = 16 ch
        const int cA = c0 + 2 * j;
        const float* b0p = xw + (size_t)cA * HWc;
        const float* b1p = b0p + HWc;

        floatx2 rm0 = *(const floatx2*)(b0p + dU);
        floatx2 r00 = *(const floatx2*)(b0p);
        floatx2 r10 = *(const floatx2*)(b0p + dD);
        floatx2 rm1 = *(const floatx2*)(b1p + dU);
        floatx2 r01 = *(const floatx2*)(b1p);
        floatx2 r11 = *(const floatx2*)(b1p + dD);
        rm0 *= mUf; r10 *= mDf; rm1 *= mUf; r11 *= mDf;   // zero padded rows

        float aLo[2], aHi[2];
        PROC1(rm0, r00, r10, 0);
        PROC1(rm1, r01, r11, 1);

        // pack agg + center as bf16 pairs (c, c+1) for both pixels
        aggLoPk[j] = cvt_pk_bf16(aLo[0], aLo[1]);
        aggHiPk[j] = cvt_pk_bf16(aHi[0], aHi[1]);
        cenLoPk[j] = cvt_pk_bf16(r00.x, r01.x);
        cenHiPk[j] = cvt_pk_bf16(r00.y, r01.y);
    }
#undef PROC1

    {   floatx2 dv = {dlo, dhi};
        *(floatx2*)&s_divp[wv][2 * l] = dv;
    }
    __syncthreads();                            // the ONLY barrier

    // per-pixel div over all 64 channels; unconditional packed select
    floatx2 sum2 = {0.f, 0.f};
    #pragma unroll
    for (int g = 0; g < 4; ++g)
        sum2 += *(const floatx2*)&s_divp[g][2 * l];
    const bool oneLo = ((sum2.x - thrv) * sclv) > 0.f;   // == sigmoid>0.5
    const bool oneHi = ((sum2.y - thrv) * sclv) > 0.f;

    uintx4 sLo0, sLo1, sHi0, sHi1;
    #pragma unroll
    for (int i = 0; i < 4; ++i) {
        sLo0[i] = oneLo ? aggLoPk[i]     : cenLoPk[i];
        sLo1[i] = oneLo ? aggLoPk[i + 4] : cenLoPk[i + 4];
        sHi0[i] = oneHi ? aggHiPk[i]     : cenHiPk[i];
        sHi1[i] = oneHi ? aggHiPk[i + 4] : cenHiPk[i + 4];
    }

    // sel[b][p][c] bf16: p = h*128 + w; lane writes 2 px x 16 ch (2x16B each)
    unsigned short* sb =
        selws + ((size_t)(b * HWc + h * Wc + 2 * l)) * Cc + c0;
    *(uintx4*)(sb)           = sLo0;            // px 2l,   c0..c0+7
    *(uintx4*)(sb + 8)       = sLo1;            // px 2l,   c0+8..c0+15
    *(uintx4*)(sb + Cc)      = sHi0;            // px 2l+1, c0..c0+7
    *(uintx4*)(sb + Cc + 8)  = sHi1;            // px 2l+1, c0+8..c0+15
}

// K2: out[b][o][p] = sum_c core[o][c] * sel[b][p][c].  No LDS, no barrier.
__global__ __launch_bounds__(256, 4) void gemm_kernel(
    const float* __restrict__ core,
    const unsigned short* __restrict__ selws, float* __restrict__ out)
{
    const int tid = threadIdx.x;
    const int l   = tid & 63;
    const int wv  = tid >> 6;                   // wave 0..3
    const int b   = blockIdx.x & 7;             // same XCD as producer
    const int pc  = blockIdx.x >> 3;            // p-chunk 0..127
    const int p0  = pc * 128;

    const int o0   = wv * 16;                   // wave's o-tile
    const int n    = l & 15;
    const int quad = l >> 4;

    // A-fragments: core[o0+n][k], k = quad*8+j (A0: k 0..31, A1: k 32..63)
    const float* arow = core + (size_t)(o0 + n) * Cc + quad * 8;
    const floatx4 af0 = *(const floatx4*)(arow);
    const floatx4 af1 = *(const floatx4*)(arow + 4);
    const floatx4 af2 = *(const floatx4*)(arow + 32);
    const floatx4 af3 = *(const floatx4*)(arow + 36);
    union { unsigned u[4]; short8 s; } A0, A1;
    A0.u[0] = cvt_pk_bf16(af0.x, af0.y); A0.u[1] = cvt_pk_bf16(af0.z, af0.w);
    A0.u[2] = cvt_pk_bf16(af1.x, af1.y); A0.u[3] = cvt_pk_bf16(af1.z, af1.w);
    A1.u[0] = cvt_pk_bf16(af2.x, af2.y); A1.u[1] = cvt_pk_bf16(af2.z, af2.w);
    A1.u[2] = cvt_pk_bf16(af3.x, af3.y); A1.u[3] = cvt_pk_bf16(af3.z, af3.w);

    const unsigned short* sb = selws + (size_t)b * HWc * Cc;
    float* outb = out + (size_t)b * Oc * HWc;

    #pragma unroll
    for (int t = 0; t < 8; ++t) {               // 8 p-tiles of 16
        const int p = p0 + t * 16 + n;
        // B-fragment: B[k=quad*8+j][n] = sel[p][quad*8+j] - contiguous 16B
        const short8 b0 = *(const short8*)(sb + (size_t)p * Cc + quad * 8);
        const short8 b1 = *(const short8*)(sb + (size_t)p * Cc + 32 + quad * 8);
        floatx4 acc = {0.f, 0.f, 0.f, 0.f};
        acc = __builtin_amdgcn_mfma_f32_16x16x32_bf16(A0.s, b0, acc, 0, 0, 0);
        acc = __builtin_amdgcn_mfma_f32_16x16x32_bf16(A1.s, b1, acc, 0, 0, 0);
        #pragma unroll
        for (int r = 0; r < 4; ++r) {
            const int o = o0 + quad * 4 + r;
            outb[(size_t)o * HWc + p] = acc[r];
        }
    }
}

extern "C" void kernel_launch(void* const* d_in, const int* in_sizes, int n_in,
                              void* d_out, int out_size, void* d_ws, size_t ws_size,
                              hipStream_t stream) {
    const float* x    = (const float*)d_in[0];
    const float* core = (const float*)d_in[1];
    const float* peri = (const float*)d_in[2];
    const float* thr  = (const float*)d_in[3];
    const float* scl  = (const float*)d_in[4];
    float* out = (float*)d_out;
    unsigned short* selws = (unsigned short*)d_ws;  // 16 MiB bf16 [b][p][c]

    sel_kernel<<<dim3(Bc * Hc), dim3(256), 0, stream>>>(
        x, peri, thr, scl, selws);
    gemm_kernel<<<dim3(Bc * Hc), dim3(256), 0, stream>>>(
        core, selws, out);
}